// Round 14
// baseline (63.677 us; speedup 1.0000x reference)
//
#include <hip/hip_runtime.h>

// ConvTranspose4d via bf16 MFMA (R14 = R13 + 2-row waves + class-segmented grid).
// Gather: out[co,f,od,oh,ow] = sum_{ci,i,kd,kh,kw} x[ci,f+i,id,ih,iw]*W[ci,co,i,kd,kh,kw]
//   id=(od+1-kd)/2 parity-valid; kd in {0,2} (od odd) / {1} (od even); same kh. kw: ow
//   even->{1}, odd->{0,2}; iw pair (n,n+1) covers all kw of one column pair.
// GEMM per class: M=16 (8 co + pad), K=8ci*3i*ND*NH*2c, N=16 cols/parity; one wave does
//   even+odd column tiles x TWO oh rows (oh, oh+2: same parity/class) sharing:
//   - A-frags identical for both rows (weight traffic per output halved)
//   - h-rows overlap for ph-odd classes (rows r0,r0+1,r0+2 serve both tiles): 12 loads
//     per 4 MFMA (was 16 per 2).
// Class-segmented wid space -> blocks are class-homogeneous (R13 blocks mixed classes ->
//   block makespan = slowest). R13 proven: XCD swizzle (FETCH 68->16MB), batched loads +
//   sched_barrier. R12 lesson: keep 2 aligned dword loads per pair.
// ph-odd row pairing: 47 rows -> last pair (45,46) overlaps (44,45); row 45 written by
//   two waves with bit-identical values (same K-order) - benign.

typedef float  f32x4  __attribute__((ext_vector_type(4)));
typedef short  bf16x8 __attribute__((ext_vector_type(8)));
typedef unsigned int u32;
typedef u32    u32x4  __attribute__((ext_vector_type(4)));
typedef float  f2u    __attribute__((ext_vector_type(2), aligned(4)));

namespace {
constexpr int T_ = 8, D_ = 24, H_ = 48, W_ = 48;
constexpr int TO = 6, DO_ = 47, HO = 95, WO = 95;
constexpr int XCS = T_ * D_ * H_ * W_;
constexpr int XFS = D_ * H_ * W_;
constexpr int XDS = H_ * W_;
constexpr long OCS = (long)TO * DO_ * HO * WO;
constexpr int OFS = DO_ * HO * WO;
constexpr int ODS = HO * WO;

// classes: 0:(pd1,ph1) 1:(pd1,ph0) 2:(pd0,ph1) 3:(pd0,ph0)
constexpr int AG[4] = {24, 12, 12, 8};
constexpr int AOFFC[8] = {0, 3072, 6144, 7680, 9216, 10752, 12288, 13312};  // shorts

__global__ __launch_bounds__(256) void pack_kernel(const float* __restrict__ w,
                                                   unsigned short* __restrict__ A) {
  const int tid = blockIdx.x * 256 + threadIdx.x;
  const int nthr = gridDim.x * 256;
  const int NDs[4] = {2, 2, 1, 1}, NHs[4] = {2, 1, 2, 1}, KR[4] = {192, 96, 96, 48};
  for (int c = 0; c < 4; ++c) {
    for (int pw = 0; pw < 2; ++pw) {
      const int cnt = AG[c] * 128;
      for (int e = tid; e < cnt; e += nthr) {
        const int j = e & 7, r = (e >> 3) & 15, g = e >> 7;
        const int k = g * 8 + j;
        float v = 0.f;
        if (r < 8 && k < KR[c]) {
          int gg, a = 0, b = 0, cc;
          if (c == 0)      { gg = g;               a = (j >> 2) & 1; b = (j >> 1) & 1; cc = j & 1; }
          else if (c == 1) { gg = 2 * g + (j >> 2); a = (j >> 1) & 1;                  cc = j & 1; }
          else if (c == 2) { gg = 2 * g + (j >> 2); b = (j >> 1) & 1;                  cc = j & 1; }
          else             { gg = 4 * g + (j >> 1);                                    cc = j & 1; }
          if (gg < 24) {
            const int ci = gg / 3, i = gg - 3 * (gg / 3);
            const int kd = (NDs[c] == 2) ? (a ? 2 : 0) : 1;
            const int kh = (NHs[c] == 2) ? (b ? 2 : 0) : 1;
            int kw = -1;
            if (cc == 0) kw = pw ? 0 : 1;
            else if (pw) kw = 2;                       // pw==0,cc==1 -> zero slot
            if (kw >= 0) v = w[ci * 648 + r * 81 + i * 27 + kd * 9 + kh * 3 + kw];
          }
        }
        u32 u = __float_as_uint(v);
        u += 0x7FFFu + ((u >> 16) & 1u);               // RNE to bf16
        A[AOFFC[c * 2 + pw] + e] = (unsigned short)(u >> 16);
      }
    }
  }
}

template<int PD, int PH>
__device__ __forceinline__ void wave_body(
    const float* __restrict__ x, const unsigned short* __restrict__ A,
    float* __restrict__ out, int f, int od, int r0, int blk, int lane)
{
  constexpr int CLS = (PD && PH) ? 0 : PD ? 1 : PH ? 2 : 3;
  constexpr int NSTEP = (CLS == 0) ? 6 : (CLS == 3) ? 2 : 3;
  constexpr int BSZ   = (CLS == 0) ? 2 : (CLS == 3) ? 2 : 3;   // steps per load batch
  constexpr int NB    = NSTEP / BSZ;                           // 3/1/1/1
  constexpr int NPAIR = (PH == 1) ? 6 : 8;                     // load pairs per step
  // tile d-order into the pair array (verified vs R11 per-class ptr order):
  constexpr int T0_[4] = {PH ? 1 : 0, PH ? 0 : 2, 4, PH ? 3 : 6};
  constexpr int T1_[4] = {PH ? 2 : 1, PH ? 1 : 3, 5, PH ? 4 : 7};

  const int c15 = lane & 15, q = lane >> 4;
  const int n = blk * 16 + c15;                        // x[n], x[n+1] feed this col pair
  const int id0 = PD ? ((od + 1) >> 1) : (od >> 1);
  const int hs = (n < 47) ? 1 : 0;                     // clamp last x[n+1] (zero-A slots)
  const int pb = f * XFS + id0 * XDS + r0 * W_ + n;

  const unsigned short* Ae = A + AOFFC[CLS * 2 + 0] + c15 * 8;
  const unsigned short* Ao = A + AOFFC[CLS * 2 + 1] + c15 * 8;

  f32x4 accE0 = {0,0,0,0}, accO0 = {0,0,0,0};          // row r0 tile (oh = 2*r0+PH)
  f32x4 accE1 = {0,0,0,0}, accO1 = {0,0,0,0};          // row r0+1 tile

  #pragma unroll
  for (int bt = 0; bt < NB; ++bt) {
    u32 BL[BSZ][NPAIR], BH[BSZ][NPAIR];
    bf16x8 ae[BSZ], ao[BSZ];
    #pragma unroll
    for (int sb = 0; sb < BSZ; ++sb) {
      const int G = (bt * BSZ + sb) * 4 + q;
      ae[sb] = *reinterpret_cast<const bf16x8*>(Ae + G * 128);
      ao[sb] = *reinterpret_cast<const bf16x8*>(Ao + G * 128);
      if constexpr (CLS == 0) {                        // pairs [e][t]: depth e, h-row t
        const int ci = G / 3, i = G - 3 * (G / 3);
        const float* p0 = x + pb + ci * XCS + i * XFS;
        #pragma unroll
        for (int e = 0; e < 2; ++e)
          #pragma unroll
          for (int t = 0; t < 3; ++t) {
            const float* p = p0 - e * XDS + t * W_;
            BL[sb][e * 3 + t] = __float_as_uint(p[0]);
            BH[sb][e * 3 + t] = __float_as_uint(p[hs]);
          }
      } else if constexpr (CLS == 1) {                 // pairs [g][e][r]
        #pragma unroll
        for (int g = 0; g < 2; ++g) {
          const int gg = 2 * G + g, ci = gg / 3, i = gg - 3 * (gg / 3);
          const float* p0 = x + pb + ci * XCS + i * XFS;
          #pragma unroll
          for (int e = 0; e < 2; ++e)
            #pragma unroll
            for (int r = 0; r < 2; ++r) {
              const float* p = p0 - e * XDS + r * W_;
              BL[sb][g * 4 + e * 2 + r] = __float_as_uint(p[0]);
              BH[sb][g * 4 + e * 2 + r] = __float_as_uint(p[hs]);
            }
        }
      } else if constexpr (CLS == 2) {                 // pairs [g][t]
        #pragma unroll
        for (int g = 0; g < 2; ++g) {
          const int gg = 2 * G + g, ci = gg / 3, i = gg - 3 * (gg / 3);
          const float* p0 = x + pb + ci * XCS + i * XFS;
          #pragma unroll
          for (int t = 0; t < 3; ++t) {
            const float* p = p0 + t * W_;
            BL[sb][g * 3 + t] = __float_as_uint(p[0]);
            BH[sb][g * 3 + t] = __float_as_uint(p[hs]);
          }
        }
      } else {                                         // pairs [d][r]; pad k>=48 clamped
        #pragma unroll
        for (int d = 0; d < 4; ++d) {
          int gg = 4 * G + d; gg = (gg > 23) ? 23 : gg;
          const float* p0 = x + pb + (gg / 3) * XCS + (gg - 3 * (gg / 3)) * XFS;
          #pragma unroll
          for (int r = 0; r < 2; ++r) {
            const float* p = p0 + r * W_;
            BL[sb][d * 2 + r] = __float_as_uint(p[0]);
            BH[sb][d * 2 + r] = __float_as_uint(p[hs]);
          }
        }
      }
    }
    __builtin_amdgcn_sched_barrier(0);                 // loads above, consumers below
    #pragma unroll
    for (int sb = 0; sb < BSZ; ++sb) {
      u32 dE[NPAIR], dO[NPAIR];
      #pragma unroll
      for (int d = 0; d < NPAIR; ++d) {
        dE[d] = __builtin_amdgcn_perm(BH[sb][d], BL[sb][d], 0x07060302u);
        dO[d] = __builtin_amdgcn_perm(BL[sb][d], BH[sb][d], 0x07060302u);
      }
      const u32x4 ue0 = {dE[T0_[0]], dE[T0_[1]], dE[T0_[2]], dE[T0_[3]]};
      const u32x4 uo0 = {dO[T0_[0]], dO[T0_[1]], dO[T0_[2]], dO[T0_[3]]};
      const u32x4 ue1 = {dE[T1_[0]], dE[T1_[1]], dE[T1_[2]], dE[T1_[3]]};
      const u32x4 uo1 = {dO[T1_[0]], dO[T1_[1]], dO[T1_[2]], dO[T1_[3]]};
      accE0 = __builtin_amdgcn_mfma_f32_16x16x32_bf16(ae[sb], __builtin_bit_cast(bf16x8, ue0), accE0, 0, 0, 0);
      accO0 = __builtin_amdgcn_mfma_f32_16x16x32_bf16(ao[sb], __builtin_bit_cast(bf16x8, uo0), accO0, 0, 0, 0);
      accE1 = __builtin_amdgcn_mfma_f32_16x16x32_bf16(ae[sb], __builtin_bit_cast(bf16x8, ue1), accE1, 0, 0, 0);
      accO1 = __builtin_amdgcn_mfma_f32_16x16x32_bf16(ao[sb], __builtin_bit_cast(bf16x8, uo1), accO1, 0, 0, 0);
    }
  }

  if (lane < 32) {                                     // rows 0..7 = co; 8..15 pad
    const bool full = !(blk == 2 && c15 == 15);        // ow=95 doesn't exist
    #pragma unroll
    for (int tile = 0; tile < 2; ++tile) {
      const int oh = 2 * (r0 + tile) + PH;
      const long ob = (long)f * OFS + (long)od * ODS + (long)oh * HO + blk * 32 + 2 * c15;
      const f32x4 aE = tile ? accE1 : accE0;
      const f32x4 aO = tile ? accO1 : accO0;
      #pragma unroll
      for (int j = 0; j < 4; ++j) {
        float* po = out + (long)(q * 4 + j) * OCS + ob;
        if (full) { f2u v; v.x = aE[j]; v.y = aO[j]; *reinterpret_cast<f2u*>(po) = v; }
        else      { po[0] = aE[j]; }
      }
    }
  }
}

// class-segmented wid space; per class: f(6) x odc x ohp(24 row-pairs) x blk(3)
constexpr int W0 = 6 * 23 * 24 * 3;        // 9936  (pd1,ph1)
constexpr int W1 = W0 + 6 * 23 * 24 * 3;   // 19872 (pd1,ph0)
constexpr int W2 = W1 + 6 * 24 * 24 * 3;   // 30240 (pd0,ph1)
constexpr int NWAVES = W2 + 6 * 24 * 24 * 3;  // 40608 (pd0,ph0)
constexpr int NBLK = NWAVES / 4;           // 10152 (%8 == 0)

__global__ __launch_bounds__(256) void convt4d_kernel(
    const float* __restrict__ x, const unsigned short* __restrict__ A,
    float* __restrict__ out)
{
  constexpr int qq = NBLK / 8;             // 1269; bijective XCD swizzle (NBLK%8==0)
  const int bid = blockIdx.x;
  const int L = (bid & 7) * qq + (bid >> 3);
  const int wid = L * 4 + (int)(threadIdx.x >> 6);
  const int lane = threadIdx.x & 63;

  if (wid < W0) {                                      // pd1, ph1
    int w2 = wid; const int blk = w2 % 3; w2 /= 3;
    const int ohp = w2 % 24; w2 /= 24;
    const int odc = w2 % 23; const int f = w2 / 23;
    wave_body<1, 1>(x, A, out, f, 2 * odc + 1, (ohp == 23) ? 45 : 2 * ohp, blk, lane);
  } else if (wid < W1) {                               // pd1, ph0
    int w2 = wid - W0; const int blk = w2 % 3; w2 /= 3;
    const int ohp = w2 % 24; w2 /= 24;
    const int odc = w2 % 23; const int f = w2 / 23;
    wave_body<1, 0>(x, A, out, f, 2 * odc + 1, 2 * ohp, blk, lane);
  } else if (wid < W2) {                               // pd0, ph1
    int w2 = wid - W1; const int blk = w2 % 3; w2 /= 3;
    const int ohp = w2 % 24; w2 /= 24;
    const int odc = w2 % 24; const int f = w2 / 24;
    wave_body<0, 1>(x, A, out, f, 2 * odc, (ohp == 23) ? 45 : 2 * ohp, blk, lane);
  } else {                                             // pd0, ph0
    int w2 = wid - W2; const int blk = w2 % 3; w2 /= 3;
    const int ohp = w2 % 24; w2 /= 24;
    const int odc = w2 % 24; const int f = w2 / 24;
    wave_body<0, 0>(x, A, out, f, 2 * odc, 2 * ohp, blk, lane);
  }
}
}  // namespace

extern "C" void kernel_launch(void* const* d_in, const int* in_sizes, int n_in,
                              void* d_out, int out_size, void* d_ws, size_t ws_size,
                              hipStream_t stream) {
  const float* x = (const float*)d_in[0];
  const float* w = (const float*)d_in[1];
  float* out = (float*)d_out;
  unsigned short* A = (unsigned short*)d_ws;           // 14336 shorts = 28 KB
  hipLaunchKernelGGL(pack_kernel, dim3(8), dim3(256), 0, stream, w, A);
  hipLaunchKernelGGL(convt4d_kernel, dim3(NBLK), dim3(256), 0, stream, x, A, out);
}

// Round 15
// 57.993 us; speedup vs baseline: 1.0980x; 1.0980x over previous
//
#include <hip/hip_runtime.h>

// ConvTranspose4d via bf16 MFMA (R15 = R13 + blk folded into wave, software-pipelined).
// Gather: out[co,f,od,oh,ow] = sum_{ci,i,kd,kh,kw} x[ci,f+i,id,ih,iw]*W[ci,co,i,kd,kh,kw]
//   id=(od+1-kd)/2 parity-valid; kd in {0,2} (od odd) / {1} (od even); same kh.
//   kw: ow even->{1}, odd->{0,2}; iw pair (n,n+1) covers one column pair.
// GEMM per class: M=16 (8 co + pad), K=8ci*3i*ND*NH*2c, N=16 cols/parity; one wave now
//   covers ALL THREE 32-col blocks of its (f,od,oh) row: A-frags loaded once (was 3x),
//   ping-pong load batches pipeline across blks (stall windows ~6 -> ~2 per row).
// wid order = R13's ((f*47+od)*95+oh): consecutive wids share x rows (R14 lesson: the
//   class-segmented order quadrupled FETCH 16->63MB; ordering IS the L2 lever).
// Kept: XCD bijective swizzle (FETCH 68->16MB, R13), batched loads + sched_barrier
//   (R13), 2 aligned dword loads per pair (R12 lesson), pack_kernel A-table (R11).

typedef float  f32x4  __attribute__((ext_vector_type(4)));
typedef short  bf16x8 __attribute__((ext_vector_type(8)));
typedef unsigned int u32;
typedef u32    u32x4  __attribute__((ext_vector_type(4)));
typedef float  f2u    __attribute__((ext_vector_type(2), aligned(4)));

namespace {
constexpr int T_ = 8, D_ = 24, H_ = 48, W_ = 48;
constexpr int TO = 6, DO_ = 47, HO = 95, WO = 95;
constexpr int XCS = T_ * D_ * H_ * W_;
constexpr int XFS = D_ * H_ * W_;
constexpr int XDS = H_ * W_;
constexpr long OCS = (long)TO * DO_ * HO * WO;
constexpr int OFS = DO_ * HO * WO;
constexpr int ODS = HO * WO;

// classes: 0:(pd1,ph1) 1:(pd1,ph0) 2:(pd0,ph1) 3:(pd0,ph0)
constexpr int AG[4] = {24, 12, 12, 8};
constexpr int AOFFC[8] = {0, 3072, 6144, 7680, 9216, 10752, 12288, 13312};  // shorts

__global__ __launch_bounds__(256) void pack_kernel(const float* __restrict__ w,
                                                   unsigned short* __restrict__ A) {
  const int tid = blockIdx.x * 256 + threadIdx.x;
  const int nthr = gridDim.x * 256;
  const int NDs[4] = {2, 2, 1, 1}, NHs[4] = {2, 1, 2, 1}, KR[4] = {192, 96, 96, 48};
  for (int c = 0; c < 4; ++c) {
    for (int pw = 0; pw < 2; ++pw) {
      const int cnt = AG[c] * 128;
      for (int e = tid; e < cnt; e += nthr) {
        const int j = e & 7, r = (e >> 3) & 15, g = e >> 7;
        const int k = g * 8 + j;
        float v = 0.f;
        if (r < 8 && k < KR[c]) {
          int gg, a = 0, b = 0, cc;
          if (c == 0)      { gg = g;               a = (j >> 2) & 1; b = (j >> 1) & 1; cc = j & 1; }
          else if (c == 1) { gg = 2 * g + (j >> 2); a = (j >> 1) & 1;                  cc = j & 1; }
          else if (c == 2) { gg = 2 * g + (j >> 2); b = (j >> 1) & 1;                  cc = j & 1; }
          else             { gg = 4 * g + (j >> 1);                                    cc = j & 1; }
          if (gg < 24) {
            const int ci = gg / 3, i = gg - 3 * (gg / 3);
            const int kd = (NDs[c] == 2) ? (a ? 2 : 0) : 1;
            const int kh = (NHs[c] == 2) ? (b ? 2 : 0) : 1;
            int kw = -1;
            if (cc == 0) kw = pw ? 0 : 1;
            else if (pw) kw = 2;                      // pw==0,cc==1 -> zero slot
            if (kw >= 0) v = w[ci * 648 + r * 81 + i * 27 + kd * 9 + kh * 3 + kw];
          }
        }
        u32 u = __float_as_uint(v);
        u += 0x7FFFu + ((u >> 16) & 1u);              // RNE to bf16
        A[AOFFC[c * 2 + pw] + e] = (unsigned short)(u >> 16);
      }
    }
  }
}

template<int PD, int PH>
__device__ __forceinline__ void wave_body(
    const float* __restrict__ x, const unsigned short* __restrict__ A,
    float* __restrict__ out, int f, int od, int oh, int lane)
{
  constexpr int CLS = (PD && PH) ? 0 : PD ? 1 : PH ? 2 : 3;
  constexpr int NSTEP = (CLS == 0) ? 6 : (CLS == 3) ? 2 : 3;
  constexpr int BSZ   = (CLS == 3) ? 2 : 3;            // K-steps per load batch
  constexpr int NB    = NSTEP / BSZ;                   // batches per blk: 2/1/1/1
  constexpr int NW    = 3 * NB;                        // pipelined work items
  const int c15 = lane & 15, q = lane >> 4;
  const int id0 = PD ? ((od + 1) >> 1) : (od >> 1);
  const int ih0 = PH ? ((oh + 1) >> 1) : (oh >> 1);
  const int pbase = f * XFS + id0 * XDS + ih0 * W_ + c15;

  // A fragments: once per wave (R13 paid this 3x)
  bf16x8 afe[NSTEP], afo[NSTEP];
  {
    const unsigned short* Ae = A + AOFFC[CLS * 2 + 0] + c15 * 8;
    const unsigned short* Ao = A + AOFFC[CLS * 2 + 1] + c15 * 8;
    #pragma unroll
    for (int s = 0; s < NSTEP; ++s) {
      const int g = s * 4 + q;
      afe[s] = *reinterpret_cast<const bf16x8*>(Ae + g * 128);
      afo[s] = *reinterpret_cast<const bf16x8*>(Ao + g * 128);
    }
  }

  f32x4 accE[3], accO[3];
  #pragma unroll
  for (int b = 0; b < 3; ++b) { accE[b] = {0,0,0,0}; accO[b] = {0,0,0,0}; }

  // 4 row pointers for step-group G at column base pb (same per-class order as R11/R13)
  auto ptrs = [&](int G, int pb, const float* p[4]) {
    if constexpr (CLS == 0) {
      const int ci = G / 3, i = G - 3 * (G / 3);
      const float* p0 = x + pb + ci * XCS + i * XFS;
      p[0] = p0; p[1] = p0 - W_; p[2] = p0 - XDS; p[3] = p0 - XDS - W_;
    } else if constexpr (CLS == 1) {
      const int g0 = 2 * G, g1 = 2 * G + 1;
      const float* p0 = x + pb + (g0 / 3) * XCS + (g0 - 3 * (g0 / 3)) * XFS;
      const float* p1 = x + pb + (g1 / 3) * XCS + (g1 - 3 * (g1 / 3)) * XFS;
      p[0] = p0; p[1] = p0 - XDS; p[2] = p1; p[3] = p1 - XDS;
    } else if constexpr (CLS == 2) {
      const int g0 = 2 * G, g1 = 2 * G + 1;
      const float* p0 = x + pb + (g0 / 3) * XCS + (g0 - 3 * (g0 / 3)) * XFS;
      const float* p1 = x + pb + (g1 / 3) * XCS + (g1 - 3 * (g1 / 3)) * XFS;
      p[0] = p0; p[1] = p0 - W_; p[2] = p1; p[3] = p1 - W_;
    } else {
      #pragma unroll
      for (int d = 0; d < 4; ++d) {
        int gg = 4 * G + d; gg = (gg > 23) ? 23 : gg;
        p[d] = x + pb + (gg / 3) * XCS + (gg - 3 * (gg / 3)) * XFS;
      }
    }
  };

  // work item w: blk = w/NB, batch bt = w%NB (w literal after unroll -> all folds)
  auto LOADW = [&](int w, u32 (&BL)[BSZ][4], u32 (&BH)[BSZ][4]) {
    const int blk = w / NB, bt = w % NB;
    const int pb = pbase + blk * 16;
    const int hs = (blk == 2 && c15 == 15) ? 0 : 1;    // clamp x[48] (zero-A slots only)
    #pragma unroll
    for (int sb = 0; sb < BSZ; ++sb) {
      const float* p[4]; ptrs((bt * BSZ + sb) * 4 + q, pb, p);
      #pragma unroll
      for (int d = 0; d < 4; ++d) {
        BL[sb][d] = __float_as_uint(p[d][0]);          // x[n]
        BH[sb][d] = __float_as_uint(p[d][hs]);         // x[n+1] (or clamp at n=47)
      }
    }
  };
  auto COMPW = [&](int w, u32 (&BL)[BSZ][4], u32 (&BH)[BSZ][4]) {
    const int blk = w / NB, bt = w % NB;
    #pragma unroll
    for (int sb = 0; sb < BSZ; ++sb) {
      const int s = bt * BSZ + sb;
      u32 dE[4], dO[4];
      #pragma unroll
      for (int d = 0; d < 4; ++d) {
        dE[d] = __builtin_amdgcn_perm(BH[sb][d], BL[sb][d], 0x07060302u);
        dO[d] = __builtin_amdgcn_perm(BL[sb][d], BH[sb][d], 0x07060302u);
      }
      const u32x4 ue = {dE[0], dE[1], dE[2], dE[3]};
      const u32x4 uo = {dO[0], dO[1], dO[2], dO[3]};
      accE[blk] = __builtin_amdgcn_mfma_f32_16x16x32_bf16(afe[s], __builtin_bit_cast(bf16x8, ue), accE[blk], 0, 0, 0);
      accO[blk] = __builtin_amdgcn_mfma_f32_16x16x32_bf16(afo[s], __builtin_bit_cast(bf16x8, uo), accO[blk], 0, 0, 0);
    }
  };

  u32 B0L[BSZ][4], B0H[BSZ][4], B1L[BSZ][4], B1H[BSZ][4];
  LOADW(0, B0L, B0H);
  #pragma unroll
  for (int w = 0; w < NW; ++w) {
    if (w + 1 < NW) {                                  // prefetch next item's loads
      if ((w + 1) & 1) LOADW(w + 1, B1L, B1H);
      else             LOADW(w + 1, B0L, B0H);
    }
    __builtin_amdgcn_sched_barrier(0);                 // loads above, consumers below
    if (w & 1) COMPW(w, B1L, B1H);
    else       COMPW(w, B0L, B0H);
  }

  if (lane < 32) {                                     // rows 0..7 = co; 8..15 pad
    #pragma unroll
    for (int blk = 0; blk < 3; ++blk) {
      const long ob = (long)f * OFS + (long)od * ODS + (long)oh * HO + blk * 32 + 2 * c15;
      const bool full = !(blk == 2 && c15 == 15);      // ow=95 doesn't exist
      #pragma unroll
      for (int j = 0; j < 4; ++j) {
        float* po = out + (long)(q * 4 + j) * OCS + ob;
        if (full) { f2u v; v.x = accE[blk][j]; v.y = accO[blk][j]; *reinterpret_cast<f2u*>(po) = v; }
        else      { po[0] = accE[blk][j]; }
      }
    }
  }
}

constexpr int NWAVES = 6 * 47 * 95;                    // 26790
constexpr int NBLK = (NWAVES + 3) / 4;                 // 6698

__global__ __launch_bounds__(256) void convt4d_kernel(
    const float* __restrict__ x, const unsigned short* __restrict__ A,
    float* __restrict__ out)
{
  // bijective XCD swizzle (m204; NBLK%8=2): consecutive work ids -> same XCD L2
  constexpr int qq = NBLK / 8, rr = NBLK % 8;          // 837, 2
  const int bid = blockIdx.x;
  const int xcd = bid % 8, ii = bid / 8;
  const int base = (xcd < rr) ? xcd * (qq + 1) : rr * (qq + 1) + (xcd - rr) * qq;
  const int wid = (base + ii) * 4 + (int)(threadIdx.x >> 6);
  if (wid >= NWAVES) return;
  const int lane = threadIdx.x & 63;
  const int oh = wid % 95;
  const int rest = wid / 95;
  const int od = rest % 47, f = rest / 47;
  if (od & 1) {
    if (oh & 1) wave_body<1, 1>(x, A, out, f, od, oh, lane);
    else        wave_body<1, 0>(x, A, out, f, od, oh, lane);
  } else {
    if (oh & 1) wave_body<0, 1>(x, A, out, f, od, oh, lane);
    else        wave_body<0, 0>(x, A, out, f, od, oh, lane);
  }
}
}  // namespace

extern "C" void kernel_launch(void* const* d_in, const int* in_sizes, int n_in,
                              void* d_out, int out_size, void* d_ws, size_t ws_size,
                              hipStream_t stream) {
  const float* x = (const float*)d_in[0];
  const float* w = (const float*)d_in[1];
  float* out = (float*)d_out;
  unsigned short* A = (unsigned short*)d_ws;           // 14336 shorts = 28 KB
  hipLaunchKernelGGL(pack_kernel, dim3(8), dim3(256), 0, stream, w, A);
  hipLaunchKernelGGL(convt4d_kernel, dim3(NBLK), dim3(256), 0, stream, x, A, out);
}

// Round 16
// 52.221 us; speedup vs baseline: 1.2194x; 1.1105x over previous
//
#include <hip/hip_runtime.h>

// ConvTranspose4d via bf16 MFMA (R16 = R15 + E/O fold into one MFMA + depth-3 prefetch).
// Gather: out[co,f,od,oh,ow] = sum_{ci,i,kd,kh,kw} x[ci,f+i,id,ih,iw]*W[ci,co,i,kd,kh,kw]
//   id=(od+1-kd)/2 parity-valid; kd in {0,2} (od odd) / {1} (od even); same kh.
//   Column pair (ow=2n, 2n+1) consumes x[n] (c=0 slot) and x[n+1] (c=1 slot).
// E/O FOLD: A rows 0-7 = co weights for EVEN ow (c0:kw1, c1:0); rows 8-15 = co weights
//   for ODD ow re-slotted to dE order (c0:kw2, c1:kw0) -> ONE MFMA/step, shared B (dE),
//   M fully used (R11-R15 wasted rows 8-15 as zero pad). Halves MFMA+perm+A-loads.
// Depth-3 prefetch: 3 rotating batch buffers, 2 batches in flight across waits.
// Kept: R15 wid order (f,od,oh; blk folded), XCD swizzle (FETCH 16MB), batched loads,
//   2 aligned dword loads/pair (R12), pack table in d_ws (R11).
// Store: lanes q<2 = even columns, q>=2 = odd; per instruction covers full 64B lines.

typedef float  f32x4  __attribute__((ext_vector_type(4)));
typedef short  bf16x8 __attribute__((ext_vector_type(8)));
typedef unsigned int u32;
typedef u32    u32x4  __attribute__((ext_vector_type(4)));

namespace {
constexpr int T_ = 8, D_ = 24, H_ = 48, W_ = 48;
constexpr int TO = 6, DO_ = 47, HO = 95, WO = 95;
constexpr int XCS = T_ * D_ * H_ * W_;
constexpr int XFS = D_ * H_ * W_;
constexpr int XDS = H_ * W_;
constexpr long OCS = (long)TO * DO_ * HO * WO;
constexpr int OFS = DO_ * HO * WO;
constexpr int ODS = HO * WO;

// classes: 0:(pd1,ph1) 1:(pd1,ph0) 2:(pd0,ph1) 3:(pd0,ph0); groups = K_pad/8
constexpr int AG[4] = {24, 12, 12, 8};
constexpr int AOFF[4] = {0, 3072, 4608, 6144};         // shorts; total 7168 = 14 KB

__global__ __launch_bounds__(256) void pack_kernel(const float* __restrict__ w,
                                                   unsigned short* __restrict__ A) {
  const int tid = blockIdx.x * 256 + threadIdx.x;
  const int nthr = gridDim.x * 256;
  const int NDs[4] = {2, 2, 1, 1}, NHs[4] = {2, 1, 2, 1}, KR[4] = {192, 96, 96, 48};
  for (int c = 0; c < 4; ++c) {
    const int cnt = AG[c] * 128;                       // [g][r(16)][j(8)] shorts
    for (int e = tid; e < cnt; e += nthr) {
      const int j = e & 7, r = (e >> 3) & 15, g = e >> 7;
      const int k = g * 8 + j;
      float v = 0.f;
      if (k < KR[c]) {
        int gg, a = 0, b = 0, cc;
        if (c == 0)      { gg = g;                a = (j >> 2) & 1; b = (j >> 1) & 1; cc = j & 1; }
        else if (c == 1) { gg = 2 * g + (j >> 2); a = (j >> 1) & 1;                   cc = j & 1; }
        else if (c == 2) { gg = 2 * g + (j >> 2); b = (j >> 1) & 1;                   cc = j & 1; }
        else             { gg = 4 * g + (j >> 1);                                     cc = j & 1; }
        if (gg < 24) {
          const int ci = gg / 3, i = gg - 3 * (gg / 3);
          const int kd = (NDs[c] == 2) ? (a ? 2 : 0) : 1;
          const int kh = (NHs[c] == 2) ? (b ? 2 : 0) : 1;
          const int co = r & 7;
          // rows 0-7: EVEN ow (c0 -> kw1, c1 -> zero)
          // rows 8-15: ODD ow in dE slot order (c0 = x[n] -> kw2, c1 = x[n+1] -> kw0)
          int kw = (r < 8) ? (cc == 0 ? 1 : -1) : (cc == 0 ? 2 : 0);
          if (kw >= 0) v = w[ci * 648 + co * 81 + i * 27 + kd * 9 + kh * 3 + kw];
        }
      }
      u32 u = __float_as_uint(v);
      u += 0x7FFFu + ((u >> 16) & 1u);                 // RNE to bf16
      A[AOFF[c] + e] = (unsigned short)(u >> 16);
    }
  }
}

template<int PD, int PH>
__device__ __forceinline__ void wave_body(
    const float* __restrict__ x, const unsigned short* __restrict__ A,
    float* __restrict__ out, int f, int od, int oh, int lane)
{
  constexpr int CLS = (PD && PH) ? 0 : PD ? 1 : PH ? 2 : 3;
  constexpr int NSTEP = (CLS == 0) ? 6 : (CLS == 3) ? 2 : 3;
  constexpr int BSZ   = (CLS == 3) ? 2 : 3;            // K-steps per load batch
  constexpr int NB    = NSTEP / BSZ;                   // batches per blk: 2/1/1/1
  constexpr int NW    = 3 * NB;                        // pipelined work items
  const int c15 = lane & 15, q = lane >> 4;
  const int id0 = PD ? ((od + 1) >> 1) : (od >> 1);
  const int ih0 = PH ? ((oh + 1) >> 1) : (oh >> 1);
  const int pbase = f * XFS + id0 * XDS + ih0 * W_ + c15;

  // A fragments (one fold-table per class), once per wave
  bf16x8 af[NSTEP];
  {
    const unsigned short* Ap = A + AOFF[CLS] + c15 * 8;
    #pragma unroll
    for (int s = 0; s < NSTEP; ++s)
      af[s] = *reinterpret_cast<const bf16x8*>(Ap + (s * 4 + q) * 128);
  }

  f32x4 acc[3];
  #pragma unroll
  for (int b = 0; b < 3; ++b) acc[b] = {0, 0, 0, 0};

  // 4 row pointers for step-group G at column base pb (same per-class order as R11/R15)
  auto ptrs = [&](int G, int pb, const float* p[4]) {
    if constexpr (CLS == 0) {
      const int ci = G / 3, i = G - 3 * (G / 3);
      const float* p0 = x + pb + ci * XCS + i * XFS;
      p[0] = p0; p[1] = p0 - W_; p[2] = p0 - XDS; p[3] = p0 - XDS - W_;
    } else if constexpr (CLS == 1) {
      const int g0 = 2 * G, g1 = 2 * G + 1;
      const float* p0 = x + pb + (g0 / 3) * XCS + (g0 - 3 * (g0 / 3)) * XFS;
      const float* p1 = x + pb + (g1 / 3) * XCS + (g1 - 3 * (g1 / 3)) * XFS;
      p[0] = p0; p[1] = p0 - XDS; p[2] = p1; p[3] = p1 - XDS;
    } else if constexpr (CLS == 2) {
      const int g0 = 2 * G, g1 = 2 * G + 1;
      const float* p0 = x + pb + (g0 / 3) * XCS + (g0 - 3 * (g0 / 3)) * XFS;
      const float* p1 = x + pb + (g1 / 3) * XCS + (g1 - 3 * (g1 / 3)) * XFS;
      p[0] = p0; p[1] = p0 - W_; p[2] = p1; p[3] = p1 - W_;
    } else {
      #pragma unroll
      for (int d = 0; d < 4; ++d) {
        int gg = 4 * G + d; gg = (gg > 23) ? 23 : gg;
        p[d] = x + pb + (gg / 3) * XCS + (gg - 3 * (gg / 3)) * XFS;
      }
    }
  };

  auto LOADW = [&](int w, u32 (&BL)[BSZ][4], u32 (&BH)[BSZ][4]) {
    const int blk = w / NB, bt = w % NB;
    const int pb = pbase + blk * 16;
    const int hs = (blk == 2 && c15 == 15) ? 0 : 1;    // clamp x[48] (discarded col only)
    #pragma unroll
    for (int sb = 0; sb < BSZ; ++sb) {
      const float* p[4]; ptrs((bt * BSZ + sb) * 4 + q, pb, p);
      #pragma unroll
      for (int d = 0; d < 4; ++d) {
        BL[sb][d] = __float_as_uint(p[d][0]);          // x[n]
        BH[sb][d] = __float_as_uint(p[d][hs]);         // x[n+1] (or clamp at n=47)
      }
    }
  };
  auto COMPW = [&](int w, u32 (&BL)[BSZ][4], u32 (&BH)[BSZ][4]) {
    const int blk = w / NB, bt = w % NB;
    #pragma unroll
    for (int sb = 0; sb < BSZ; ++sb) {
      const int s = bt * BSZ + sb;
      u32 dE[4];
      #pragma unroll
      for (int d = 0; d < 4; ++d)                       // lo16=bf(x[n]), hi16=bf(x[n+1])
        dE[d] = __builtin_amdgcn_perm(BH[sb][d], BL[sb][d], 0x07060302u);
      const u32x4 ue = {dE[0], dE[1], dE[2], dE[3]};
      acc[blk] = __builtin_amdgcn_mfma_f32_16x16x32_bf16(af[s], __builtin_bit_cast(bf16x8, ue), acc[blk], 0, 0, 0);
    }
  };

  u32 BL[3][BSZ][4], BH[3][BSZ][4];                     // depth-3 rotating buffers
  LOADW(0, BL[0], BH[0]);
  if (NW > 1) LOADW(1, BL[1], BH[1]);
  #pragma unroll
  for (int w = 0; w < NW; ++w) {
    if (w + 2 < NW) LOADW(w + 2, BL[(w + 2) % 3], BH[(w + 2) % 3]);
    __builtin_amdgcn_sched_barrier(0);                  // loads above, consumers below
    COMPW(w, BL[w % 3], BH[w % 3]);
  }

  // D rows 0-7 = co (even ow), rows 8-15 = co (odd ow); row = q*4+j, col = c15.
  const int isO = (q >= 2);
  const int co0 = (q & 1) * 4;
  #pragma unroll
  for (int blk = 0; blk < 3; ++blk) {
    const int ow = blk * 32 + 2 * c15 + isO;
    if (ow < 95) {                                      // masks only blk2,c15=15 odd
      const long ob = (long)f * OFS + (long)od * ODS + (long)oh * HO + ow;
      #pragma unroll
      for (int j = 0; j < 4; ++j)
        out[(long)(co0 + j) * OCS + ob] = acc[blk][j];
    }
  }
}

constexpr int NWAVES = 6 * 47 * 95;                     // 26790
constexpr int NBLK = (NWAVES + 3) / 4;                  // 6698

__global__ __launch_bounds__(256) void convt4d_kernel(
    const float* __restrict__ x, const unsigned short* __restrict__ A,
    float* __restrict__ out)
{
  // bijective XCD swizzle (m204; NBLK%8=2): consecutive work ids -> same XCD L2
  constexpr int qq = NBLK / 8, rr = NBLK % 8;           // 837, 2
  const int bid = blockIdx.x;
  const int xcd = bid % 8, ii = bid / 8;
  const int base = (xcd < rr) ? xcd * (qq + 1) : rr * (qq + 1) + (xcd - rr) * qq;
  const int wid = (base + ii) * 4 + (int)(threadIdx.x >> 6);
  if (wid >= NWAVES) return;
  const int lane = threadIdx.x & 63;
  const int oh = wid % 95;
  const int rest = wid / 95;
  const int od = rest % 47, f = rest / 47;
  if (od & 1) {
    if (oh & 1) wave_body<1, 1>(x, A, out, f, od, oh, lane);
    else        wave_body<1, 0>(x, A, out, f, od, oh, lane);
  } else {
    if (oh & 1) wave_body<0, 1>(x, A, out, f, od, oh, lane);
    else        wave_body<0, 0>(x, A, out, f, od, oh, lane);
  }
}
}  // namespace

extern "C" void kernel_launch(void* const* d_in, const int* in_sizes, int n_in,
                              void* d_out, int out_size, void* d_ws, size_t ws_size,
                              hipStream_t stream) {
  const float* x = (const float*)d_in[0];
  const float* w = (const float*)d_in[1];
  float* out = (float*)d_out;
  unsigned short* A = (unsigned short*)d_ws;            // 7168 shorts = 14 KB
  hipLaunchKernelGGL(pack_kernel, dim3(8), dim3(256), 0, stream, w, A);
  hipLaunchKernelGGL(convt4d_kernel, dim3(NBLK), dim3(256), 0, stream, x, A, out);
}

// Round 17
// 44.104 us; speedup vs baseline: 1.4438x; 1.1840x over previous
//
#include <hip/hip_runtime.h>

// ConvTranspose4d via bf16 MFMA (R17 = R16 fold + block-level LDS staging).
// Gather: out[co,f,od,oh,ow] = sum_{ci,i,kd,kh,kw} x[ci,f+i,id,ih,iw]*W[ci,co,i,kd,kh,kw]
// R16 E/O fold kept: A rows 0-7 = even-ow weights (c0:kw1,c1:0), rows 8-15 = odd-ow
//   weights in dE slot order (c0:kw2,c1:kw0); one MFMA per K-step, shared B.
// R17: block = (f, od, oh-group-of-4). The 4 waves' x rows overlap heavily (ih span =
//   3 rows); stage the union ONCE into LDS (72*ND rows x 48 floats, stride 52 = 16B
//   aligned, pads zeroed so n=47 tail reads 0.0), then B pairs come from LDS.
//   Theory: per-CU TA/L1 line throughput was the shared wall (~70K line-cy/CU of 125K;
//   4 quarters x distinct rows per scattered dword load, 4x redundancy across waves) --
//   explains R8/R15 occupancy/wave-count insensitivity. LDS cuts line traffic ~5x.
// Kept: XCD swizzle, og-fastest wid order (L2 locality, R14 lesson), pack table (R11).

typedef float  f32x4  __attribute__((ext_vector_type(4)));
typedef float  f4a    __attribute__((ext_vector_type(4)));
typedef short  bf16x8 __attribute__((ext_vector_type(8)));
typedef unsigned int u32;

namespace {
constexpr int T_ = 8, D_ = 24, H_ = 48, W_ = 48;
constexpr int TO = 6, DO_ = 47, HO = 95, WO = 95;
constexpr int XCS = T_ * D_ * H_ * W_;
constexpr int XFS = D_ * H_ * W_;
constexpr int XDS = H_ * W_;
constexpr long OCS = (long)TO * DO_ * HO * WO;
constexpr int OFS = DO_ * HO * WO;
constexpr int ODS = HO * WO;

constexpr int AG[4] = {24, 12, 12, 8};
constexpr int AOFF[4] = {0, 3072, 4608, 6144};         // shorts; total 7168 = 14 KB
constexpr int LSTR = 52;                               // LDS row stride (floats)

__global__ __launch_bounds__(256) void pack_kernel(const float* __restrict__ w,
                                                   unsigned short* __restrict__ A) {
  const int tid = blockIdx.x * 256 + threadIdx.x;
  const int nthr = gridDim.x * 256;
  const int NDs[4] = {2, 2, 1, 1}, NHs[4] = {2, 1, 2, 1}, KR[4] = {192, 96, 96, 48};
  for (int c = 0; c < 4; ++c) {
    const int cnt = AG[c] * 128;                       // [g][r(16)][j(8)] shorts
    for (int e = tid; e < cnt; e += nthr) {
      const int j = e & 7, r = (e >> 3) & 15, g = e >> 7;
      const int k = g * 8 + j;
      float v = 0.f;
      if (k < KR[c]) {
        int gg, a = 0, b = 0, cc;
        if (c == 0)      { gg = g;                a = (j >> 2) & 1; b = (j >> 1) & 1; cc = j & 1; }
        else if (c == 1) { gg = 2 * g + (j >> 2); a = (j >> 1) & 1;                   cc = j & 1; }
        else if (c == 2) { gg = 2 * g + (j >> 2); b = (j >> 1) & 1;                   cc = j & 1; }
        else             { gg = 4 * g + (j >> 1);                                     cc = j & 1; }
        if (gg < 24) {
          const int ci = gg / 3, i = gg - 3 * (gg / 3);
          const int kd = (NDs[c] == 2) ? (a ? 2 : 0) : 1;
          const int kh = (NHs[c] == 2) ? (b ? 2 : 0) : 1;
          const int co = r & 7;
          int kw = (r < 8) ? (cc == 0 ? 1 : -1) : (cc == 0 ? 2 : 0);
          if (kw >= 0) v = w[ci * 648 + co * 81 + i * 27 + kd * 9 + kh * 3 + kw];
        }
      }
      u32 u = __float_as_uint(v);
      u += 0x7FFFu + ((u >> 16) & 1u);                 // RNE to bf16
      A[AOFF[c] + e] = (unsigned short)(u >> 16);
    }
  }
}

template<int PD, int PH>
__device__ __forceinline__ void wave_body(
    const float* __restrict__ lds, const unsigned short* __restrict__ A,
    float* __restrict__ out, int f, int od, int oh, int ihb, int lane)
{
  constexpr int CLS = (PD && PH) ? 0 : PD ? 1 : PH ? 2 : 3;
  constexpr int NSTEP = (CLS == 0) ? 6 : (CLS == 3) ? 2 : 3;
  const int c15 = lane & 15, q = lane >> 4;
  const int th = ((oh + PH) >> 1) - ihb;               // top h-row (0..2)

  bf16x8 af[NSTEP];
  {
    const unsigned short* Ap = A + AOFF[CLS] + c15 * 8;
    #pragma unroll
    for (int s = 0; s < NSTEP; ++s)
      af[s] = *reinterpret_cast<const bf16x8*>(Ap + (s * 4 + q) * 128);
  }

  // LDS row linear index: ((ci*3+i)*ND + e)*3 + t   (ND = PD+1)
  f32x4 acc[3];
  #pragma unroll
  for (int b = 0; b < 3; ++b) acc[b] = {0, 0, 0, 0};

  #pragma unroll
  for (int blk = 0; blk < 3; ++blk) {
    const int n = blk * 16 + c15;
    #pragma unroll
    for (int s = 0; s < NSTEP; ++s) {
      const int G = s * 4 + q;
      int rows[4];
      if constexpr (CLS == 0) {                        // gg=G; d = (e,tdel)
        const int base = G * 6;
        rows[0] = base + th;     rows[1] = base + th - 1;
        rows[2] = base + 3 + th; rows[3] = base + 3 + th - 1;
      } else if constexpr (CLS == 1) {                 // d = (gpar, e)
        const int b0 = (2 * G) * 6, b1 = (2 * G + 1) * 6;
        rows[0] = b0 + th; rows[1] = b0 + 3 + th;
        rows[2] = b1 + th; rows[3] = b1 + 3 + th;
      } else if constexpr (CLS == 2) {                 // d = (gpar, tdel)
        const int b0 = (2 * G) * 3, b1 = (2 * G + 1) * 3;
        rows[0] = b0 + th; rows[1] = b0 + th - 1;
        rows[2] = b1 + th; rows[3] = b1 + th - 1;
      } else {                                         // d = gg&3 (clamped pad)
        #pragma unroll
        for (int d = 0; d < 4; ++d) {
          int gg = 4 * G + d; gg = (gg > 23) ? 23 : gg;
          rows[d] = gg * 3 + th;
        }
      }
      u32 dE[4];
      #pragma unroll
      for (int d = 0; d < 4; ++d) {
        const int a0 = rows[d] * LSTR + n;
        const u32 bl = __float_as_uint(lds[a0]);       // x[n]
        const u32 bh = __float_as_uint(lds[a0 + 1]);   // x[n+1] (pad 0.0 at n=47)
        dE[d] = __builtin_amdgcn_perm(bh, bl, 0x07060302u);  // lo=bf(x[n]), hi=bf(x[n+1])
      }
      typedef u32 u32x4v __attribute__((ext_vector_type(4)));
      const u32x4v ue = {dE[0], dE[1], dE[2], dE[3]};
      acc[blk] = __builtin_amdgcn_mfma_f32_16x16x32_bf16(af[s], __builtin_bit_cast(bf16x8, ue), acc[blk], 0, 0, 0);
    }
  }

  // D rows 0-7 = co (even ow), 8-15 = co (odd ow); row = q*4+j, col = c15.
  const int isO = (q >= 2);
  const int co0 = (q & 1) * 4;
  #pragma unroll
  for (int blk = 0; blk < 3; ++blk) {
    const int ow = blk * 32 + 2 * c15 + isO;
    if (ow < 95) {
      const long ob = (long)f * OFS + (long)od * ODS + (long)oh * HO + ow;
      #pragma unroll
      for (int j = 0; j < 4; ++j)
        out[(long)(co0 + j) * OCS + ob] = acc[blk][j];
    }
  }
}

constexpr int NBLK = 6 * 47 * 24;                      // 6768 (og groups of 4 oh rows)

__global__ __launch_bounds__(256) void convt4d_kernel(
    const float* __restrict__ x, const unsigned short* __restrict__ A,
    float* __restrict__ out)
{
  __shared__ float lds[144 * LSTR];                    // 29952 B max (ND=2)

  constexpr int qq = NBLK / 8;                         // 846 (NBLK%8==0)
  const int bid = blockIdx.x;
  const int L = (bid & 7) * qq + (bid >> 3);           // bijective XCD swizzle
  const int og = L % 24;
  const int rest = L / 24;
  const int od = rest % 47, f = rest / 47;

  const int tid = threadIdx.x;
  const int pd = od & 1;
  const int ND = pd + 1;
  const int id0 = pd ? ((od + 1) >> 1) : (od >> 1);
  const int ihb = og * 2;
  const int NROWS = 72 * ND;

  // zero the per-row pad (floats 48..51) so n=47 reads x[n+1]=0.0, never junk/NaN
  for (int r = tid; r < NROWS; r += 256)
    *reinterpret_cast<f32x4*>(&lds[r * LSTR + 48]) = f32x4{0.f, 0.f, 0.f, 0.f};
  // stage union of x rows: row = ((ci*3+i)*ND+e)*3+t, 12 dwordx4 chunks per row
  for (int c = tid; c < NROWS * 12; c += 256) {
    const int row = c / 12, ch = c % 12;
    const int t = row % 3;
    const int r2 = row / 3;
    const int e = pd ? (r2 & 1) : 0;
    const int r3 = pd ? (r2 >> 1) : r2;
    const int i = r3 % 3, ci = r3 / 3;
    int ih = ihb + t; if (ih > 47) ih = 47;            // og=23 t=2 row unused by compute
    const float* src = x + ci * XCS + (f + i) * XFS + (id0 - e) * XDS + ih * W_ + ch * 4;
    *reinterpret_cast<f32x4*>(&lds[row * LSTR + ch * 4]) = *reinterpret_cast<const f4a*>(src);
  }
  __syncthreads();

  const int w = tid >> 6, lane = tid & 63;
  int oh = og * 4 + w;
  if (oh > 94) oh = 93;                                // og=23,w=3: duplicate of w=1 (benign)
  if (pd) {
    if (oh & 1) wave_body<1, 1>(lds, A, out, f, od, oh, ihb, lane);
    else        wave_body<1, 0>(lds, A, out, f, od, oh, ihb, lane);
  } else {
    if (oh & 1) wave_body<0, 1>(lds, A, out, f, od, oh, ihb, lane);
    else        wave_body<0, 0>(lds, A, out, f, od, oh, ihb, lane);
  }
}
}  // namespace

extern "C" void kernel_launch(void* const* d_in, const int* in_sizes, int n_in,
                              void* d_out, int out_size, void* d_ws, size_t ws_size,
                              hipStream_t stream) {
  const float* x = (const float*)d_in[0];
  const float* w = (const float*)d_in[1];
  float* out = (float*)d_out;
  unsigned short* A = (unsigned short*)d_ws;           // 7168 shorts = 14 KB
  hipLaunchKernelGGL(pack_kernel, dim3(8), dim3(256), 0, stream, w, A);
  hipLaunchKernelGGL(convt4d_kernel, dim3(NBLK), dim3(256), 0, stream, x, A, out);
}

// Round 18
// 43.647 us; speedup vs baseline: 1.4589x; 1.0105x over previous
//
#include <hip/hip_runtime.h>

// ConvTranspose4d via bf16 MFMA (R18 = R17 + bf16-PACKED LDS).
// Gather: out[co,f,od,oh,ow] = sum_{ci,i,kd,kh,kw} x[ci,f+i,id,ih,iw]*W[ci,co,i,kd,kh,kw]
// R16 E/O fold: A rows 0-7 = even-ow weights (c0:kw1,c1:0), rows 8-15 = odd-ow weights
//   in dE slot order (c0:kw2,c1:kw0); one MFMA per K-step, shared B.
// R17 LDS staging: block = (f,od,4-oh-group); x-row union staged once (TA wall removed).
// R18: LDS holds PRE-PACKED u32 = (bf16(x[n]) | bf16(x[n+1])<<16) -- the exact dE word.
//   Compute: 1 ds_read_b32 per (row,n) (was 2) and ZERO perms (moved to staging, done
//   once per block not once per wave: 432->108 perm-instrs/block). Pad pass deleted
//   (packed[47] hi = 0 built at staging). R17 accounting: LDS pipe ~80K cyc/CU of 115K
//   (432 reads + 3.3M conflicts) was the floor. Same truncation + MFMA order -> absmax
//   bit-identical (0.0078125).
// Kept: XCD swizzle, og-fastest order (L2), pack table (R11), 16B staging loads.

typedef float  f32x4  __attribute__((ext_vector_type(4)));
typedef float  f4a    __attribute__((ext_vector_type(4)));
typedef short  bf16x8 __attribute__((ext_vector_type(8)));
typedef unsigned int u32;
typedef u32    u32x4  __attribute__((ext_vector_type(4)));

namespace {
constexpr int T_ = 8, D_ = 24, H_ = 48, W_ = 48;
constexpr int TO = 6, DO_ = 47, HO = 95, WO = 95;
constexpr int XCS = T_ * D_ * H_ * W_;
constexpr int XFS = D_ * H_ * W_;
constexpr int XDS = H_ * W_;
constexpr long OCS = (long)TO * DO_ * HO * WO;
constexpr int OFS = DO_ * HO * WO;
constexpr int ODS = HO * WO;

constexpr int AG[4] = {24, 12, 12, 8};
constexpr int AOFF[4] = {0, 3072, 4608, 6144};         // shorts; total 7168 = 14 KB
constexpr int LSTR = 52;                               // LDS row stride (u32 units)

__global__ __launch_bounds__(256) void pack_kernel(const float* __restrict__ w,
                                                   unsigned short* __restrict__ A) {
  const int tid = blockIdx.x * 256 + threadIdx.x;
  const int nthr = gridDim.x * 256;
  const int NDs[4] = {2, 2, 1, 1}, NHs[4] = {2, 1, 2, 1}, KR[4] = {192, 96, 96, 48};
  for (int c = 0; c < 4; ++c) {
    const int cnt = AG[c] * 128;                       // [g][r(16)][j(8)] shorts
    for (int e = tid; e < cnt; e += nthr) {
      const int j = e & 7, r = (e >> 3) & 15, g = e >> 7;
      const int k = g * 8 + j;
      float v = 0.f;
      if (k < KR[c]) {
        int gg, a = 0, b = 0, cc;
        if (c == 0)      { gg = g;                a = (j >> 2) & 1; b = (j >> 1) & 1; cc = j & 1; }
        else if (c == 1) { gg = 2 * g + (j >> 2); a = (j >> 1) & 1;                   cc = j & 1; }
        else if (c == 2) { gg = 2 * g + (j >> 2); b = (j >> 1) & 1;                   cc = j & 1; }
        else             { gg = 4 * g + (j >> 1);                                     cc = j & 1; }
        if (gg < 24) {
          const int ci = gg / 3, i = gg - 3 * (gg / 3);
          const int kd = (NDs[c] == 2) ? (a ? 2 : 0) : 1;
          const int kh = (NHs[c] == 2) ? (b ? 2 : 0) : 1;
          const int co = r & 7;
          int kw = (r < 8) ? (cc == 0 ? 1 : -1) : (cc == 0 ? 2 : 0);
          if (kw >= 0) v = w[ci * 648 + co * 81 + i * 27 + kd * 9 + kh * 3 + kw];
        }
      }
      u32 u = __float_as_uint(v);
      u += 0x7FFFu + ((u >> 16) & 1u);                 // RNE to bf16
      A[AOFF[c] + e] = (unsigned short)(u >> 16);
    }
  }
}

template<int PD, int PH>
__device__ __forceinline__ void wave_body(
    const u32* __restrict__ lds, const unsigned short* __restrict__ A,
    float* __restrict__ out, int f, int od, int oh, int ihb, int lane)
{
  constexpr int CLS = (PD && PH) ? 0 : PD ? 1 : PH ? 2 : 3;
  constexpr int NSTEP = (CLS == 0) ? 6 : (CLS == 3) ? 2 : 3;
  const int c15 = lane & 15, q = lane >> 4;
  const int th = ((oh + PH) >> 1) - ihb;               // top h-row (0..2)

  bf16x8 af[NSTEP];
  {
    const unsigned short* Ap = A + AOFF[CLS] + c15 * 8;
    #pragma unroll
    for (int s = 0; s < NSTEP; ++s)
      af[s] = *reinterpret_cast<const bf16x8*>(Ap + (s * 4 + q) * 128);
  }

  f32x4 acc[3];
  #pragma unroll
  for (int b = 0; b < 3; ++b) acc[b] = {0, 0, 0, 0};

  #pragma unroll
  for (int blk = 0; blk < 3; ++blk) {
    const int n = blk * 16 + c15;
    #pragma unroll
    for (int s = 0; s < NSTEP; ++s) {
      const int G = s * 4 + q;
      int rows[4];
      if constexpr (CLS == 0) {                        // gg=G; d = (e,tdel)
        const int base = G * 6;
        rows[0] = base + th;     rows[1] = base + th - 1;
        rows[2] = base + 3 + th; rows[3] = base + 3 + th - 1;
      } else if constexpr (CLS == 1) {                 // d = (gpar, e)
        const int b0 = (2 * G) * 6, b1 = (2 * G + 1) * 6;
        rows[0] = b0 + th; rows[1] = b0 + 3 + th;
        rows[2] = b1 + th; rows[3] = b1 + 3 + th;
      } else if constexpr (CLS == 2) {                 // d = (gpar, tdel)
        const int b0 = (2 * G) * 3, b1 = (2 * G + 1) * 3;
        rows[0] = b0 + th; rows[1] = b0 + th - 1;
        rows[2] = b1 + th; rows[3] = b1 + th - 1;
      } else {                                         // d = gg&3 (clamped pad)
        #pragma unroll
        for (int d = 0; d < 4; ++d) {
          int gg = 4 * G + d; gg = (gg > 23) ? 23 : gg;
          rows[d] = gg * 3 + th;
        }
      }
      const u32x4 ue = {lds[rows[0] * LSTR + n], lds[rows[1] * LSTR + n],
                        lds[rows[2] * LSTR + n], lds[rows[3] * LSTR + n]};
      acc[blk] = __builtin_amdgcn_mfma_f32_16x16x32_bf16(af[s], __builtin_bit_cast(bf16x8, ue), acc[blk], 0, 0, 0);
    }
  }

  // D rows 0-7 = co (even ow), 8-15 = co (odd ow); row = q*4+j, col = c15.
  const int isO = (q >= 2);
  const int co0 = (q & 1) * 4;
  #pragma unroll
  for (int blk = 0; blk < 3; ++blk) {
    const int ow = blk * 32 + 2 * c15 + isO;
    if (ow < 95) {
      const long ob = (long)f * OFS + (long)od * ODS + (long)oh * HO + ow;
      #pragma unroll
      for (int j = 0; j < 4; ++j)
        out[(long)(co0 + j) * OCS + ob] = acc[blk][j];
    }
  }
}

constexpr int NBLK = 6 * 47 * 24;                      // 6768 (og groups of 4 oh rows)

__global__ __launch_bounds__(256) void convt4d_kernel(
    const float* __restrict__ x, const unsigned short* __restrict__ A,
    float* __restrict__ out)
{
  __shared__ u32 lds[144 * LSTR];                      // 29952 B max (ND=2)

  constexpr int qq = NBLK / 8;                         // 846 (NBLK%8==0)
  const int bid = blockIdx.x;
  const int L = (bid & 7) * qq + (bid >> 3);           // bijective XCD swizzle
  const int og = L % 24;
  const int rest = L / 24;
  const int od = rest % 47, f = rest / 47;

  const int tid = threadIdx.x;
  const int pd = od & 1;
  const int ND = pd + 1;
  const int id0 = pd ? ((od + 1) >> 1) : (od >> 1);
  const int ihb = og * 2;
  const int NROWS = 72 * ND;

  // stage union of x rows PRE-PACKED: lds[row*LSTR + n] = bf(x[n]) | bf(x[n+1])<<16
  // row = ((ci*3+i)*ND+e)*3+t; 12 chunks of 4 packed words per row.
  for (int c = tid; c < NROWS * 12; c += 256) {
    const int row = c / 12, ch = c % 12;
    const int t = row % 3;
    const int r2 = row / 3;
    const int e = pd ? (r2 & 1) : 0;
    const int r3 = pd ? (r2 >> 1) : r2;
    const int i = r3 % 3, ci = r3 / 3;
    int ih = ihb + t; if (ih > 47) ih = 47;            // og=23 t=2 row unused by compute
    const float* src = x + ci * XCS + (f + i) * XFS + (id0 - e) * XDS + ih * W_ + ch * 4;
    const f4a v = *reinterpret_cast<const f4a*>(src);
    const float v4 = (ch == 11) ? 0.f : src[4];        // x[48] slot must be 0 (n=47 pair)
    const u32 b0 = __float_as_uint(v.x), b1 = __float_as_uint(v.y);
    const u32 b2 = __float_as_uint(v.z), b3 = __float_as_uint(v.w);
    const u32 b4 = __float_as_uint(v4);
    const u32x4 pk = {__builtin_amdgcn_perm(b1, b0, 0x07060302u),
                      __builtin_amdgcn_perm(b2, b1, 0x07060302u),
                      __builtin_amdgcn_perm(b3, b2, 0x07060302u),
                      __builtin_amdgcn_perm(b4, b3, 0x07060302u)};
    *reinterpret_cast<u32x4*>(&lds[row * LSTR + ch * 4]) = pk;  // 16B-aligned (LSTR*4%16==0)
  }
  __syncthreads();

  const int w = tid >> 6, lane = tid & 63;
  int oh = og * 4 + w;
  if (oh > 94) oh = 93;                                // og=23,w=3: duplicate of w=1 (benign)
  if (pd) {
    if (oh & 1) wave_body<1, 1>(lds, A, out, f, od, oh, ihb, lane);
    else        wave_body<1, 0>(lds, A, out, f, od, oh, ihb, lane);
  } else {
    if (oh & 1) wave_body<0, 1>(lds, A, out, f, od, oh, ihb, lane);
    else        wave_body<0, 0>(lds, A, out, f, od, oh, ihb, lane);
  }
}
}  // namespace

extern "C" void kernel_launch(void* const* d_in, const int* in_sizes, int n_in,
                              void* d_out, int out_size, void* d_ws, size_t ws_size,
                              hipStream_t stream) {
  const float* x = (const float*)d_in[0];
  const float* w = (const float*)d_in[1];
  float* out = (float*)d_out;
  unsigned short* A = (unsigned short*)d_ws;           // 7168 shorts = 14 KB
  hipLaunchKernelGGL(pack_kernel, dim3(8), dim3(256), 0, stream, w, A);
  hipLaunchKernelGGL(convt4d_kernel, dim3(NBLK), dim3(256), 0, stream, x, A, out);
}

// Round 19
// 37.749 us; speedup vs baseline: 1.6869x; 1.1562x over previous
//
#include <hip/hip_runtime.h>

// ConvTranspose4d via bf16 MFMA (R19 = R18 + od-PAIR blocks, 512 threads).
// Gather: out[co,f,od,oh,ow] = sum_{ci,i,kd,kh,kw} x[ci,f+i,id,ih,iw]*W[ci,co,i,kd,kh,kw]
// R16 E/O fold: A rows 0-7 even-ow weights (c0:kw1,c1:0), rows 8-15 odd-ow (c0:kw2,
//   c1:kw0); one MFMA/K-step. R17 LDS staging (TA wall). R18 bf16-packed LDS words.
// R19: od=2p and od=2p+1 consume the SAME depth planes {p,p+1} -> one block stages the
//   144-row union ONCE for 8 waves (4 on od=2p, 4 on od=2p+1). Staged rows per od-pair
//   216->144; blocks 6768->3456 (fixed costs halve). R18 post-mortem: conflicts halved
//   with no dur change -> LDS wasn't binding; per-block serial structure (stage+barrier
//   +fixed) is the target. Row layout [ (ci*3+i)*2+e ][t]; pd0 waves read e=1 plane
//   (row = gg*6+3+th). Math order unchanged -> absmax bit-identical 0.0078125.
// od=46 leftover: pd1 half exits after syncthreads (staging done; no later barriers).

typedef float  f32x4  __attribute__((ext_vector_type(4)));
typedef float  f4a    __attribute__((ext_vector_type(4)));
typedef short  bf16x8 __attribute__((ext_vector_type(8)));
typedef unsigned int u32;
typedef u32    u32x4  __attribute__((ext_vector_type(4)));

namespace {
constexpr int T_ = 8, D_ = 24, H_ = 48, W_ = 48;
constexpr int TO = 6, DO_ = 47, HO = 95, WO = 95;
constexpr int XCS = T_ * D_ * H_ * W_;
constexpr int XFS = D_ * H_ * W_;
constexpr int XDS = H_ * W_;
constexpr long OCS = (long)TO * DO_ * HO * WO;
constexpr int OFS = DO_ * HO * WO;
constexpr int ODS = HO * WO;

constexpr int AG[4] = {24, 12, 12, 8};
constexpr int AOFF[4] = {0, 3072, 4608, 6144};         // shorts; total 7168 = 14 KB
constexpr int LSTR = 52;                               // LDS row stride (u32 units)

__global__ __launch_bounds__(256) void pack_kernel(const float* __restrict__ w,
                                                   unsigned short* __restrict__ A) {
  const int tid = blockIdx.x * 256 + threadIdx.x;
  const int nthr = gridDim.x * 256;
  const int NDs[4] = {2, 2, 1, 1}, NHs[4] = {2, 1, 2, 1}, KR[4] = {192, 96, 96, 48};
  for (int c = 0; c < 4; ++c) {
    const int cnt = AG[c] * 128;                       // [g][r(16)][j(8)] shorts
    for (int e = tid; e < cnt; e += nthr) {
      const int j = e & 7, r = (e >> 3) & 15, g = e >> 7;
      const int k = g * 8 + j;
      float v = 0.f;
      if (k < KR[c]) {
        int gg, a = 0, b = 0, cc;
        if (c == 0)      { gg = g;                a = (j >> 2) & 1; b = (j >> 1) & 1; cc = j & 1; }
        else if (c == 1) { gg = 2 * g + (j >> 2); a = (j >> 1) & 1;                   cc = j & 1; }
        else if (c == 2) { gg = 2 * g + (j >> 2); b = (j >> 1) & 1;                   cc = j & 1; }
        else             { gg = 4 * g + (j >> 1);                                     cc = j & 1; }
        if (gg < 24) {
          const int ci = gg / 3, i = gg - 3 * (gg / 3);
          const int kd = (NDs[c] == 2) ? (a ? 2 : 0) : 1;
          const int kh = (NHs[c] == 2) ? (b ? 2 : 0) : 1;
          const int co = r & 7;
          int kw = (r < 8) ? (cc == 0 ? 1 : -1) : (cc == 0 ? 2 : 0);
          if (kw >= 0) v = w[ci * 648 + co * 81 + i * 27 + kd * 9 + kh * 3 + kw];
        }
      }
      u32 u = __float_as_uint(v);
      u += 0x7FFFu + ((u >> 16) & 1u);                 // RNE to bf16
      A[AOFF[c] + e] = (unsigned short)(u >> 16);
    }
  }
}

template<int PD, int PH>
__device__ __forceinline__ void wave_body(
    const u32* __restrict__ lds, const unsigned short* __restrict__ A,
    float* __restrict__ out, int f, int od, int oh, int ihb, int lane)
{
  constexpr int CLS = (PD && PH) ? 0 : PD ? 1 : PH ? 2 : 3;
  constexpr int NSTEP = (CLS == 0) ? 6 : (CLS == 3) ? 2 : 3;
  const int c15 = lane & 15, q = lane >> 4;
  const int th = ((oh + PH) >> 1) - ihb;               // top h-row (0..2)

  bf16x8 af[NSTEP];
  {
    const unsigned short* Ap = A + AOFF[CLS] + c15 * 8;
    #pragma unroll
    for (int s = 0; s < NSTEP; ++s)
      af[s] = *reinterpret_cast<const bf16x8*>(Ap + (s * 4 + q) * 128);
  }

  f32x4 acc[3];
  #pragma unroll
  for (int b = 0; b < 3; ++b) acc[b] = {0, 0, 0, 0};

  // shared layout: row = ((ci*3+i)*2 + e)*3 + t ; e=0 -> plane p+1 (kd=0), e=1 -> p
  #pragma unroll
  for (int blk = 0; blk < 3; ++blk) {
    const int n = blk * 16 + c15;
    #pragma unroll
    for (int s = 0; s < NSTEP; ++s) {
      const int G = s * 4 + q;
      int rows[4];
      if constexpr (CLS == 0) {                        // gg=G; d = (e, tdel)
        const int base = G * 6;
        rows[0] = base + th;     rows[1] = base + th - 1;
        rows[2] = base + 3 + th; rows[3] = base + 3 + th - 1;
      } else if constexpr (CLS == 1) {                 // d = (gpar, e)
        const int b0 = (2 * G) * 6, b1 = (2 * G + 1) * 6;
        rows[0] = b0 + th; rows[1] = b0 + 3 + th;
        rows[2] = b1 + th; rows[3] = b1 + 3 + th;
      } else if constexpr (CLS == 2) {                 // d = (gpar, tdel); e=1 plane
        const int b0 = (2 * G) * 6 + 3, b1 = (2 * G + 1) * 6 + 3;
        rows[0] = b0 + th; rows[1] = b0 + th - 1;
        rows[2] = b1 + th; rows[3] = b1 + th - 1;
      } else {                                         // d = gg&3 (clamped); e=1 plane
        #pragma unroll
        for (int d = 0; d < 4; ++d) {
          int gg = 4 * G + d; gg = (gg > 23) ? 23 : gg;
          rows[d] = gg * 6 + 3 + th;
        }
      }
      const u32x4 ue = {lds[rows[0] * LSTR + n], lds[rows[1] * LSTR + n],
                        lds[rows[2] * LSTR + n], lds[rows[3] * LSTR + n]};
      acc[blk] = __builtin_amdgcn_mfma_f32_16x16x32_bf16(af[s], __builtin_bit_cast(bf16x8, ue), acc[blk], 0, 0, 0);
    }
  }

  // D rows 0-7 = co (even ow), 8-15 = co (odd ow); row = q*4+j, col = c15.
  const int isO = (q >= 2);
  const int co0 = (q & 1) * 4;
  #pragma unroll
  for (int blk = 0; blk < 3; ++blk) {
    const int ow = blk * 32 + 2 * c15 + isO;
    if (ow < 95) {
      const long ob = (long)f * OFS + (long)od * ODS + (long)oh * HO + ow;
      #pragma unroll
      for (int j = 0; j < 4; ++j)
        out[(long)(co0 + j) * OCS + ob] = acc[blk][j];
    }
  }
}

constexpr int NBLK = 6 * 24 * 24;                      // f x od-pair x og = 3456

__global__ __launch_bounds__(512) void convt4d_kernel(
    const float* __restrict__ x, const unsigned short* __restrict__ A,
    float* __restrict__ out)
{
  __shared__ u32 lds[144 * LSTR];                      // 29952 B

  constexpr int qq = NBLK / 8;                         // 432 (NBLK%8==0)
  const int bid = blockIdx.x;
  const int L = (bid & 7) * qq + (bid >> 3);           // bijective XCD swizzle
  const int og = L % 24;
  const int rest = L / 24;
  const int odp = rest % 24, f = rest / 24;            // od pair: {2*odp, 2*odp+1}

  const int tid = threadIdx.x;
  const int ihb = og * 2;
  const int idp = odp + 1;                             // e=0 plane = p+1, e=1 plane = p

  // stage 144-row union PRE-PACKED: lds[row*LSTR+n] = bf(x[n]) | bf(x[n+1])<<16
  // row = ((ci*3+i)*2 + e)*3 + t
  for (int c = tid; c < 144 * 12; c += 512) {
    const int row = c / 12, ch = c % 12;
    const int t = row % 3;
    const int r2 = row / 3;
    const int e = r2 & 1;
    const int r3 = r2 >> 1;
    const int i = r3 % 3, ci = r3 / 3;
    int plane = idp - e; if (plane > 23) plane = 23;   // odp=23,e=0: unused, clamp OOB
    int ih = ihb + t; if (ih > 47) ih = 47;            // og=23 t=2: unused, clamp
    const float* src = x + ci * XCS + (f + i) * XFS + plane * XDS + ih * W_ + ch * 4;
    const f4a v = *reinterpret_cast<const f4a*>(src);
    const float v4 = (ch == 11) ? 0.f : src[4];        // x[48] slot must be 0 (n=47 pair)
    const u32 b0 = __float_as_uint(v.x), b1 = __float_as_uint(v.y);
    const u32 b2 = __float_as_uint(v.z), b3 = __float_as_uint(v.w);
    const u32 b4 = __float_as_uint(v4);
    const u32x4 pk = {__builtin_amdgcn_perm(b1, b0, 0x07060302u),
                      __builtin_amdgcn_perm(b2, b1, 0x07060302u),
                      __builtin_amdgcn_perm(b3, b2, 0x07060302u),
                      __builtin_amdgcn_perm(b4, b3, 0x07060302u)};
    *reinterpret_cast<u32x4*>(&lds[row * LSTR + ch * 4]) = pk;  // 16B-aligned
  }
  __syncthreads();

  const int w = tid >> 6, lane = tid & 63;
  const int half = w >> 2;                             // 0: od=2p (pd0), 1: od=2p+1 (pd1)
  const int od = 2 * odp + half;
  if (od > 46) return;                                 // odp=23 pd1 half: no od=47
  int oh = og * 4 + (w & 3);
  if (oh > 94) oh = 93;                                // og=23,w&3=3: dup of w&3=1 (benign)
  if (half) {
    if (oh & 1) wave_body<1, 1>(lds, A, out, f, od, oh, ihb, lane);
    else        wave_body<1, 0>(lds, A, out, f, od, oh, ihb, lane);
  } else {
    if (oh & 1) wave_body<0, 1>(lds, A, out, f, od, oh, ihb, lane);
    else        wave_body<0, 0>(lds, A, out, f, od, oh, ihb, lane);
  }
}
}  // namespace

extern "C" void kernel_launch(void* const* d_in, const int* in_sizes, int n_in,
                              void* d_out, int out_size, void* d_ws, size_t ws_size,
                              hipStream_t stream) {
  const float* x = (const float*)d_in[0];
  const float* w = (const float*)d_in[1];
  float* out = (float*)d_out;
  unsigned short* A = (unsigned short*)d_ws;           // 7168 shorts = 14 KB
  hipLaunchKernelGGL(pack_kernel, dim3(8), dim3(256), 0, stream, w, A);
  hipLaunchKernelGGL(convt4d_kernel, dim3(NBLK), dim3(512), 0, stream, x, A, out);
}